// Round 10
// baseline (1233.379 us; speedup 1.0000x reference)
//
#include <hip/hip_runtime.h>

// Problem dims (fp32 in / fp32 out)
#define B_    64
#define T_    512
#define DIN_  256
#define H_    512
#define DOUT_ 128

// Pipeline chunking: layer-1 consumes layer-0's output CHUNK timesteps at a time.
#define CHUNK  32
#define NCHUNK (T_ / CHUNK)     // 16
#define NGEMM  64               // gemm-worker WGs: (B_*CHUNK/128) M-tiles * (H_/128) N-tiles = 16*4

typedef _Float16 f16x8 __attribute__((ext_vector_type(8)));
typedef float    f32x4 __attribute__((ext_vector_type(4)));
typedef _Float16 half2v __attribute__((ext_vector_type(2)));

// ---------------------------------------------------------------------------
// dot of 8 f16 pairs (w,h packed as uint4) accumulated into fp32
__device__ __forceinline__ float dot8(uint4 w, uint4 h, float s) {
#if __has_builtin(__builtin_amdgcn_fdot2)
  s = __builtin_amdgcn_fdot2(__builtin_bit_cast(half2v, w.x), __builtin_bit_cast(half2v, h.x), s, false);
  s = __builtin_amdgcn_fdot2(__builtin_bit_cast(half2v, w.y), __builtin_bit_cast(half2v, h.y), s, false);
  s = __builtin_amdgcn_fdot2(__builtin_bit_cast(half2v, w.z), __builtin_bit_cast(half2v, h.z), s, false);
  s = __builtin_amdgcn_fdot2(__builtin_bit_cast(half2v, w.w), __builtin_bit_cast(half2v, h.w), s, false);
#else
  const half2v* wp = (const half2v*)&w;
  const half2v* hp = (const half2v*)&h;
#pragma unroll
  for (int q = 0; q < 4; ++q) {
    s += (float)wp[q][0] * (float)hp[q][0] + (float)wp[q][1] * (float)hp[q][1];
  }
#endif
  return s;
}

// fast branchless tanh: tanh(x) = sign(x) * (1 - 2/(e^{2|x|}+1)); |err| ~1e-6
__device__ __forceinline__ float fast_tanh(float x) {
  float a = fabsf(x);
  float e = __expf(2.f * a);
  float r = 1.f - 2.f / (e + 1.f);
  return copysignf(r, x);
}

// opaque pin: forces v's components into arch VGPRs at this point and makes
// the producing loads non-rematerializable
__device__ __forceinline__ void pin4(uint4& v) {
  asm volatile("" : "+v"(v.x), "+v"(v.y), "+v"(v.z), "+v"(v.w));
}

// LDS-only barrier: drains own ds ops (lgkmcnt) then syncs, WITHOUT the
// vmcnt(0) drain __syncthreads emits — in-flight global loads with register
// destinations (the wrapped q3 ring, the early xv loads) legally stay
// outstanding across it.
__device__ __forceinline__ void barrier_lds() {
  asm volatile("s_waitcnt lgkmcnt(0)" ::: "memory");
  __builtin_amdgcn_s_barrier();
}

// device-scope (agent) flag ops for the chunk pipeline
__device__ __forceinline__ unsigned ld_flag(const unsigned* p) {
  return __hip_atomic_load(p, __ATOMIC_RELAXED, __HIP_MEMORY_SCOPE_AGENT);
}
__device__ __forceinline__ void add_flag(unsigned* p) {
  __hip_atomic_fetch_add(p, 1u, __ATOMIC_RELEASE, __HIP_MEMORY_SCOPE_AGENT);
}
__device__ __forceinline__ void wait_flag(const unsigned* p, unsigned target) {
  // bounded spin: capacity argument guarantees progress (192 WGs <= 256 CUs,
  // 1 WG/CU forced by 146 KB LDS, producers never wait on consumers).
  for (int n = 0; n < (1 << 21); ++n) {
    if (ld_flag(p) >= target) return;
    __builtin_amdgcn_s_sleep(8);
  }
}

// ---------------------------------------------------------------------------
// Generic fp32 -> f16 conversion (memory-bound, one-shot prep)
__global__ void cvt_f32_f16(const float* __restrict__ in, _Float16* __restrict__ out, int n) {
  int idx = blockIdx.x * 256 + threadIdx.x;
  if (idx < n) out[idx] = (_Float16)in[idx];
}

__global__ void zero_flags(unsigned* __restrict__ f) {
  if (threadIdx.x < 2 * NCHUNK) f[threadIdx.x] = 0u;
}

// ---------------------------------------------------------------------------
// Prep: convert W_hh (fp32, row-major HxH) into the R2 4-split scan layout:
//   chunk c = (rsub*16 + i)*512 + tid  holds  W[4*(tid&127)+rsub][(tid>>7)*128 + i*8 .. +8)
// Scan thread tid loads chunk (rsub,i) at lane-stride 16 B -> fully coalesced.
__global__ void prep_w(const float* __restrict__ w0, const float* __restrict__ w1,
                       _Float16* __restrict__ o0, _Float16* __restrict__ o1) {
  int idx = blockIdx.x * 256 + threadIdx.x;        // 0 .. 65535 (two matrices)
  const float* src = (idx < 32768) ? w0 : w1;
  _Float16* dst = (idx < 32768) ? o0 : o1;
  int c = idx & 32767;
  int tid  = c & 511;
  int rest = c >> 9;          // 0..63
  int i    = rest & 15;
  int rsub = rest >> 4;       // 0..3
  int row = 4 * (tid & 127) + rsub;
  int kc  = (tid >> 7) * 16 + i;
#pragma unroll
  for (int e = 0; e < 8; ++e)
    dst[(size_t)c * 8 + e] = (_Float16)src[row * 512 + kc * 8 + e];
}

// ---------------------------------------------------------------------------
// GEMM: out[m,n] = sum_k X[m,k]*W[n,k] + bias1[n] + bias2[n], written as f16.
// 128x128 tile / 256 threads / 4 waves (2x2 of 64x64), BK=32 (for xproj0 only).
__global__ __launch_bounds__(256)
void gemm_xproj(const _Float16* __restrict__ X,
                const _Float16* __restrict__ W,
                const float* __restrict__ bias1,
                const float* __restrict__ bias2,
                _Float16* __restrict__ out, int K) {
  __shared__ __align__(16) _Float16 As[128 * 32];
  __shared__ __align__(16) _Float16 Bs[128 * 32];
  const int tid  = threadIdx.x;
  const int wave = tid >> 6;
  const int lane = tid & 63;
  const int wr = wave >> 1, wc = wave & 1;
  const int m0 = blockIdx.x * 128, n0 = blockIdx.y * 128;
  const int fr = lane & 15;
  const int fk = (lane >> 4) * 8;
  const int cA = (lane & 3) * 8;
  const int rsub = lane >> 2;

  f32x4 acc[4][4];
#pragma unroll
  for (int a = 0; a < 4; ++a)
#pragma unroll
    for (int b = 0; b < 4; ++b)
      acc[a][b] = (f32x4){0.f, 0.f, 0.f, 0.f};

  for (int k0 = 0; k0 < K; k0 += 32) {
    __syncthreads();
#pragma unroll
    for (int q = 0; q < 2; ++q) {
      int p = wave * 2 + q;
      int r = p * 16 + rsub;
      const _Float16* gA = X + (size_t)(m0 + r) * K + (k0 + cA);
      const _Float16* gB = W + (size_t)(n0 + r) * K + (k0 + cA);
      __builtin_amdgcn_global_load_lds(
          (const __attribute__((address_space(1))) void*)gA,
          (__attribute__((address_space(3))) void*)((char*)As + p * 1024), 16, 0, 0);
      __builtin_amdgcn_global_load_lds(
          (const __attribute__((address_space(1))) void*)gB,
          (__attribute__((address_space(3))) void*)((char*)Bs + p * 1024), 16, 0, 0);
    }
    __syncthreads();

    f16x8 af[4], bfr[4];
#pragma unroll
    for (int mt = 0; mt < 4; ++mt)
      af[mt] = *(const f16x8*)&As[(wr * 64 + mt * 16 + fr) * 32 + fk];
#pragma unroll
    for (int nt = 0; nt < 4; ++nt)
      bfr[nt] = *(const f16x8*)&Bs[(wc * 64 + nt * 16 + fr) * 32 + fk];
#pragma unroll
    for (int mt = 0; mt < 4; ++mt)
#pragma unroll
      for (int nt = 0; nt < 4; ++nt)
        acc[mt][nt] = __builtin_amdgcn_mfma_f32_16x16x32_f16(af[mt], bfr[nt], acc[mt][nt], 0, 0, 0);
  }

  const int col = lane & 15, rq = lane >> 4;
#pragma unroll
  for (int nt = 0; nt < 4; ++nt) {
    int n = n0 + wc * 64 + nt * 16 + col;
    float bias = bias1[n] + bias2[n];
#pragma unroll
    for (int mt = 0; mt < 4; ++mt) {
      int mbase = m0 + wr * 64 + mt * 16 + rq * 4;
#pragma unroll
      for (int r = 0; r < 4; ++r)
        out[(size_t)(mbase + r) * H_ + n] = (_Float16)(acc[mt][nt][r] + bias);
    }
  }
}

// ---------------------------------------------------------------------------
// Scan role, R10 = R9 with the LDS-overflow fix (smem 148480 -> 149504).
// R9's failure was hb[] extending 1 KB past the declared block — the
// wave-owned-reduce design itself is unchanged and now actually under test:
//  - dot phase byte-identical to R8 (32 reg / 16 LDS / 16 streamed, wrap ring)
//  - reduce: wave w owns quarter uw=w>>1 (rows uw*128+l, +64; pair waves
//    duplicate — each wave alone writes its ENTIRE read-quarter, so the
//    duplicate is complete and value-identical)
//  - psum ping-pong [2][4][512]: one-barrier/step bounds drift to one phase
//  - xv1/xv2 issued at the TOP of the step (R7's mistake corrected)
__device__ __forceinline__ void scan_role(
    int layer, int b,
    const uint4* __restrict__ Wg, const _Float16* __restrict__ xproj,
    _Float16* __restrict__ seq, float* __restrict__ hlast,
    unsigned* __restrict__ ca, unsigned* __restrict__ cb, char* smem)
{
  uint4* ldsW = (uint4*)smem;                                  // 128 KB (slots 32..47)
  float (*psum)[4][512] = (float (*)[4][512])(smem + 131072);  // 16 KB ping-pong partials
  _Float16 (*hb)[512] = (_Float16 (*)[512])(smem + 147456);    // 2 KB h double buffer
  const int tid = threadIdx.x;
  const int u  = tid >> 7;                  // dot-phase k-quarter 0..3 (= w>>1)
  const int w  = tid >> 6;                  // wave 0..7
  const int uw = w >> 1;                    // reduce-phase quarter (wave-owned)
  const int l  = tid & 63;
  const int R1 = uw * 128 + l;              // reduce rows: R1, R1+64
  const int R2 = R1 + 64;

  // slots 0..31 (rows +0,+1) -> 128 VGPRs, coalesced (lane stride 16 B)
  uint4 wreg[32];
#pragma unroll
  for (int i = 0; i < 32; ++i) wreg[i] = Wg[i * 512 + tid];
#pragma unroll
  for (int i = 0; i < 32; ++i) pin4(wreg[i]);

  // slots 32..47 (row+2, i=0..15) -> LDS (one-time, coalesced)
#pragma unroll
  for (int i = 0; i < 16; ++i) ldsW[i * 512 + tid] = Wg[(32 + i) * 512 + tid];

  hb[0][tid] = (_Float16)0.f;
  hb[1][tid] = (_Float16)0.f;
  __syncthreads();

  const uint4* S3 = Wg + (size_t)48 * 512 + tid;    // row+3, i=0..15 (16 slots)
  const _Float16* xp = xproj + (size_t)b * (T_ * H_);
  _Float16* sq = seq + (size_t)b * (T_ * H_);

  // q3 ring: primed ONCE; wrapped in-loop reload self-sustains across steps
  uint4 q3[4];
#pragma unroll
  for (int p = 0; p < 4; ++p) q3[p] = S3[(size_t)p * 512];

  int cur = 0;
  for (int t = 0; t < T_; ++t) {
    if (layer == 1 && (t & (CHUNK - 1)) == 0) {
      // acquire chunk t/CHUNK of xproj1 (vmcnt drain also lands q3: harmless)
      if (tid == 0) wait_flag(cb + (t / CHUNK), NGEMM);
      __syncthreads();
      __threadfence();                              // inv stale L1/L2 lines
    }
    // EARLY xv loads for the two wave-owned rows: the whole dot phase covers
    // their L2 latency; consumed only after barrier A.
    float xv1 = (float)xp[(size_t)t * H_ + R1];
    float xv2 = (float)xp[(size_t)t * H_ + R2];
    const uint4* hbu = (const uint4*)hb[cur] + u * 16;

    float a0 = 0.f, a1 = 0.f, a2 = 0.f, a3 = 0.f;   // row accumulators = 4 chains
#pragma unroll
    for (int i = 0; i < 16; ++i) {
      uint4 h = hbu[i];                             // one b128 broadcast read
      a0 = dot8(wreg[i], h, a0);
      a1 = dot8(wreg[16 + i], h, a1);
      a2 = dot8(ldsW[i * 512 + tid], h, a2);        // dense 16-B stride, conflict-free
      a3 = dot8(q3[i & 3], h, a3);
      q3[i & 3] = S3[(size_t)((i + 4) & 15) * 512]; // wrap: i>=12 loads next step's 0..3
    }
    // psum[p][u][4r+rsub]: one contiguous b128 per thread, conflict-free
    const int p = t & 1;
    *(f32x4*)&psum[p][u][4 * (tid & 127)] = (f32x4){a0, a1, a2, a3};
    barrier_lds();                                  // THE step barrier (DS drain only)

    // wave-owned reduce: rows R1, R2 of quarter uw (pair waves duplicate).
    // Lane-stride-4B dense reads, conflict-free.
    float s1 = (psum[p][0][R1] + psum[p][1][R1]) + (psum[p][2][R1] + psum[p][3][R1]);
    float s2 = (psum[p][0][R2] + psum[p][1][R2]) + (psum[p][2][R2] + psum[p][3][R2]);
    float h1 = fast_tanh(s1 + xv1);
    float h2 = fast_tanh(s2 + xv2);
    _Float16 h16a = (_Float16)h1, h16b = (_Float16)h2;
    hb[cur ^ 1][R1] = h16a;                         // own next-step quarter:
    hb[cur ^ 1][R2] = h16b;                         // wave-local RAW, no barrier B
    if (!(w & 1)) {                                 // even wave of each pair only
      if (layer == 0) {
        sq[(size_t)t * H_ + R1] = h16a;
        sq[(size_t)t * H_ + R2] = h16b;
      } else if (t == T_ - 1) {
        hlast[b * H_ + R1] = h1;
        hlast[b * H_ + R2] = h2;
      }
    }
    if (layer == 0 && (t & (CHUNK - 1)) == CHUNK - 1) {
      // chunk boundary only (1/32 steps): drain seq stores, then publish
      __syncthreads();
      if (tid == 0) { __threadfence(); add_flag(ca + (t / CHUNK)); }
    }
    cur ^= 1;
  }
}

// ---------------------------------------------------------------------------
// GEMM worker role: per chunk c, WG g computes one 128x128 tile of
// xproj1 = h1seq @ W_ih1^T + b_ih1 + b_hh1, writing IN PLACE over xproj0
// (safe: runs only after all L0 WGs finished — and thus finished reading —
// chunk c). 512 threads = 8 waves as 4x2 grid of 32x64 fragments.
__device__ __forceinline__ void gemm_role(
    int g,
    const _Float16* __restrict__ X,      // h1seq  (B,T,H) f16
    const _Float16* __restrict__ W,      // W_ih1  (H,H)   f16
    const float* __restrict__ bias1, const float* __restrict__ bias2,
    _Float16* __restrict__ out,          // xproj  (B,T,H) f16 (in-place)
    unsigned* __restrict__ ca, unsigned* __restrict__ cb, char* smem)
{
  _Float16* As = (_Float16*)smem;              // 8 KB [128][32]
  _Float16* Bs = (_Float16*)(smem + 8192);     // 8 KB [128][32]
  const int tid  = threadIdx.x;
  const int wave = tid >> 6;
  const int lane = tid & 63;
  const int wr = wave >> 1, wc = wave & 1;     // 4x2 waves, each 32 rows x 64 cols
  const int mt = g >> 2;                       // M-tile 0..15 (128 rows of 2048)
  const int n0 = (g & 3) * 128;
  const int fr = lane & 15;
  const int fk = (lane >> 4) * 8;
  const int sr  = tid >> 2;                    // staging row 0..127
  const int scq = (tid & 3) * 8;               // staging col (f16) 0/8/16/24
  const int col = lane & 15, rq = lane >> 4;
  const size_t wrow = (size_t)(n0 + sr) * H_ + scq;   // W staging addr (chunk-invariant)

  for (int c = 0; c < NCHUNK; ++c) {
    if (tid == 0) wait_flag(ca + c, B_);       // all 64 L0 WGs done with chunk c
    __syncthreads();
    __threadfence();                           // inv stale lines before reading h1seq

    // tile row jj -> batch 4*mt + (jj>>5), t = c*CHUNK + (jj&31)
    const size_t arow =
        ((size_t)(4 * mt + (sr >> 5)) * T_ + c * CHUNK + (sr & 31)) * H_ + scq;

    f32x4 acc[2][4];
#pragma unroll
    for (int m = 0; m < 2; ++m)
#pragma unroll
      for (int n = 0; n < 4; ++n)
        acc[m][n] = (f32x4){0.f, 0.f, 0.f, 0.f};

    for (int k0 = 0; k0 < H_; k0 += 32) {
      __syncthreads();
      __builtin_amdgcn_global_load_lds(
          (const __attribute__((address_space(1))) void*)(X + arow + k0),
          (__attribute__((address_space(3))) void*)((char*)As + (tid >> 6) * 1024), 16, 0, 0);
      __builtin_amdgcn_global_load_lds(
          (const __attribute__((address_space(1))) void*)(W + wrow + k0),
          (__attribute__((address_space(3))) void*)((char*)Bs + (tid >> 6) * 1024), 16, 0, 0);
      __syncthreads();                         // plain: NEEDS the vmcnt drain

      f16x8 af[2], bf[4];
#pragma unroll
      for (int m = 0; m < 2; ++m)
        af[m] = *(const f16x8*)&As[(wr * 32 + m * 16 + fr) * 32 + fk];
#pragma unroll
      for (int n = 0; n < 4; ++n)
        bf[n] = *(const f16x8*)&Bs[(wc * 64 + n * 16 + fr) * 32 + fk];
#pragma unroll
      for (int m = 0; m < 2; ++m)
#pragma unroll
        for (int n = 0; n < 4; ++n)
          acc[m][n] = __builtin_amdgcn_mfma_f32_16x16x32_f16(af[m], bf[n], acc[m][n], 0, 0, 0);
    }

#pragma unroll
    for (int n = 0; n < 4; ++n) {
      int nn = n0 + wc * 64 + n * 16 + col;
      float bias = bias1[nn] + bias2[nn];
#pragma unroll
      for (int m = 0; m < 2; ++m) {
        int jbase = wr * 32 + m * 16 + rq * 4;
#pragma unroll
        for (int r = 0; r < 4; ++r) {
          int jj = jbase + r;
          size_t row = ((size_t)(4 * mt + (jj >> 5)) * T_ + c * CHUNK + (jj & 31)) * (size_t)H_;
          out[row + nn] = (_Float16)(acc[m][n][r] + bias);
        }
      }
    }
    __syncthreads();                           // drain all threads' tile stores
    if (tid == 0) { __threadfence(); add_flag(cb + c); }
  }
}

// ---------------------------------------------------------------------------
// Fused pipeline megakernel: 192 WGs x 512 threads.
//   WG   0..63  : layer-0 scan (batch b)       — produces h1seq chunk flags ca[]
//   WG  64..127 : layer-1 scan (batch b-64)    — consumes xproj1 chunk flags cb[]
//   WG 128..191 : GEMM workers                 — ca[c] -> xproj1 tile -> cb[c]
// 146 KB LDS forces 1 WG/CU; 192 WGs <= 256 CUs all co-resident, one per CU;
// wait DAG (L1 <- GEMM <- L0) is deadlock-free.
__global__ __launch_bounds__(512)
__attribute__((amdgpu_waves_per_eu(1, 2)))
void fused_pipeline(const uint4* __restrict__ Wg0, const uint4* __restrict__ Wg1,
                    const _Float16* __restrict__ Wih1,
                    const float* __restrict__ b_ih1, const float* __restrict__ b_hh1,
                    _Float16* __restrict__ xproj, _Float16* __restrict__ h1seq,
                    float* __restrict__ hlast, unsigned* __restrict__ flags) {
  __shared__ __align__(16) char smem[149504];  // 128K ldsW + 16K psum + 2K hb (R9 was 1 KB short)
  unsigned* ca = flags;            // [NCHUNK] target B_
  unsigned* cb = flags + NCHUNK;   // [NCHUNK] target NGEMM
  const int wg = blockIdx.x;
  if (wg < 64) {
    scan_role(0, wg, Wg0, xproj, h1seq, hlast, ca, cb, smem);
  } else if (wg < 128) {
    scan_role(1, wg - 64, Wg1, xproj, h1seq, hlast, ca, cb, smem);
  } else {
    gemm_role(wg - 128, h1seq, Wih1, b_ih1, b_hh1, xproj, ca, cb, smem);
  }
}

// ---------------------------------------------------------------------------
// Final FC: out[b,o] = h2[b,:] . w_fc[o,:] + b_fc[o]   (64 x 128, tiny, pure fp32)
__global__ void fc_kernel(const float* __restrict__ h2,
                          const float* __restrict__ wfc,
                          const float* __restrict__ bfc,
                          float* __restrict__ out) {
  int b = blockIdx.x, o = threadIdx.x;
  float s = bfc[o];
  const float* hv = h2 + b * H_;
  const float* wr = wfc + (size_t)o * H_;
#pragma unroll 8
  for (int k = 0; k < H_; ++k) s += hv[k] * wr[k];
  out[b * DOUT_ + o] = s;
}

// ---------------------------------------------------------------------------
extern "C" void kernel_launch(void* const* d_in, const int* in_sizes, int n_in,
                              void* d_out, int out_size, void* d_ws, size_t ws_size,
                              hipStream_t stream) {
  const float* x     = (const float*)d_in[0];
  const float* w_ih0 = (const float*)d_in[1];
  const float* w_hh0 = (const float*)d_in[2];
  const float* b_ih0 = (const float*)d_in[3];
  const float* b_hh0 = (const float*)d_in[4];
  const float* w_ih1 = (const float*)d_in[5];
  const float* w_hh1 = (const float*)d_in[6];
  const float* b_ih1 = (const float*)d_in[7];
  const float* b_hh1 = (const float*)d_in[8];
  const float* w_fc  = (const float*)d_in[9];
  const float* b_fc  = (const float*)d_in[10];

  char* ws = (char*)d_ws;
  _Float16* Ws0   = (_Float16*)(ws + 0);          // 512 KB  (w_hh0 scan layout)
  _Float16* Ws1   = (_Float16*)(ws + 524288);     // 512 KB  (w_hh1 scan layout)
  _Float16* Wih0  = (_Float16*)(ws + 1048576);    // 256 KB  (w_ih0 f16)
  _Float16* Wih1  = (_Float16*)(ws + 1310720);    // 512 KB  (w_ih1 f16)
  float*    h2    = (float*)   (ws + 2097152);    // 128 KB  (final hidden, fp32)
  unsigned* flags = (unsigned*)(ws + 3145728);    // 128 B   (chunk counters)
  _Float16* xproj = (_Float16*)(ws + 4194304);    // 32 MB   (xproj0, overwritten by xproj1)
  _Float16* xf16  = (_Float16*)(ws + 37748736);   // x as f16, then dead...
  _Float16* h1seq = (_Float16*)(ws + 37748736);   // ...h1 sequence f16 (32 MB)

  // 1) one-shot conversions to f16 + flag reset (re-zeroed every graph iteration)
  cvt_f32_f16<<<32768, 256, 0, stream>>>(x, xf16, B_ * T_ * DIN_);
  cvt_f32_f16<<<512,   256, 0, stream>>>(w_ih0, Wih0, H_ * DIN_);
  cvt_f32_f16<<<1024,  256, 0, stream>>>(w_ih1, Wih1, H_ * H_);
  prep_w<<<256, 256, 0, stream>>>(w_hh0, w_hh1, Ws0, Ws1);
  zero_flags<<<1, 64, 0, stream>>>(flags);

  // 2) xproj0 = x @ w_ih0^T + b_ih0 + b_hh0   (M=32768, K=256)
  gemm_xproj<<<dim3(256, 4), 256, 0, stream>>>(xf16, Wih0, b_ih0, b_hh0, xproj, DIN_);

  // 3+4+5) fused: layer-0 scan || chunked xproj1 GEMM || layer-1 scan
  fused_pipeline<<<192, 512, 0, stream>>>((const uint4*)Ws0, (const uint4*)Ws1,
                                          Wih1, b_ih1, b_hh1,
                                          xproj, h1seq, h2, flags);

  // 6) FC -> d_out (fp32, 64x128)
  fc_kernel<<<B_, DOUT_, 0, stream>>>(h2, w_fc, b_fc, (float*)d_out);
}

// Round 11
// 1191.995 us; speedup vs baseline: 1.0347x; 1.0347x over previous
//
#include <hip/hip_runtime.h>

// Problem dims (fp32 in / fp32 out)
#define B_    64
#define T_    512
#define DIN_  256
#define H_    512
#define DOUT_ 128

// Pipeline chunking: layer-1 consumes layer-0's output CHUNK timesteps at a time.
#define CHUNK  32
#define NCHUNK (T_ / CHUNK)     // 16
#define NGEMM  64               // gemm-worker WGs: (B_*CHUNK/128) M-tiles * (H_/128) N-tiles = 16*4

typedef _Float16 f16x8 __attribute__((ext_vector_type(8)));
typedef float    f32x4 __attribute__((ext_vector_type(4)));
typedef _Float16 half2v __attribute__((ext_vector_type(2)));

// ---------------------------------------------------------------------------
// dot of 8 f16 pairs (w,h packed as uint4) accumulated into fp32
__device__ __forceinline__ float dot8(uint4 w, uint4 h, float s) {
#if __has_builtin(__builtin_amdgcn_fdot2)
  s = __builtin_amdgcn_fdot2(__builtin_bit_cast(half2v, w.x), __builtin_bit_cast(half2v, h.x), s, false);
  s = __builtin_amdgcn_fdot2(__builtin_bit_cast(half2v, w.y), __builtin_bit_cast(half2v, h.y), s, false);
  s = __builtin_amdgcn_fdot2(__builtin_bit_cast(half2v, w.z), __builtin_bit_cast(half2v, h.z), s, false);
  s = __builtin_amdgcn_fdot2(__builtin_bit_cast(half2v, w.w), __builtin_bit_cast(half2v, h.w), s, false);
#else
  const half2v* wp = (const half2v*)&w;
  const half2v* hp = (const half2v*)&h;
#pragma unroll
  for (int q = 0; q < 4; ++q) {
    s += (float)wp[q][0] * (float)hp[q][0] + (float)wp[q][1] * (float)hp[q][1];
  }
#endif
  return s;
}

// fast branchless tanh: tanh(x) = sign(x) * (1 - 2/(e^{2|x|}+1)); |err| ~1e-6
__device__ __forceinline__ float fast_tanh(float x) {
  float a = fabsf(x);
  float e = __expf(2.f * a);
  float r = 1.f - 2.f / (e + 1.f);
  return copysignf(r, x);
}

// opaque pin: forces v's components into arch VGPRs at this point and makes
// the producing loads non-rematerializable
__device__ __forceinline__ void pin4(uint4& v) {
  asm volatile("" : "+v"(v.x), "+v"(v.y), "+v"(v.z), "+v"(v.w));
}

// LDS-only barrier: drains own ds ops (lgkmcnt) then syncs, WITHOUT the
// vmcnt(0) drain __syncthreads emits — in-flight global ops with register
// destinations legally stay outstanding across it (R3/R5-proven correct).
__device__ __forceinline__ void barrier_lds() {
  asm volatile("s_waitcnt lgkmcnt(0)" ::: "memory");
  __builtin_amdgcn_s_barrier();
}

// device-scope (agent) flag ops for the chunk pipeline
__device__ __forceinline__ unsigned ld_flag(const unsigned* p) {
  return __hip_atomic_load(p, __ATOMIC_RELAXED, __HIP_MEMORY_SCOPE_AGENT);
}
__device__ __forceinline__ void add_flag(unsigned* p) {
  __hip_atomic_fetch_add(p, 1u, __ATOMIC_RELEASE, __HIP_MEMORY_SCOPE_AGENT);
}
__device__ __forceinline__ void wait_flag(const unsigned* p, unsigned target) {
  // bounded spin: capacity argument guarantees progress (192 WGs <= 256 CUs,
  // 1 WG/CU forced by 138 KB LDS, producers never wait on consumers).
  for (int n = 0; n < (1 << 21); ++n) {
    if (ld_flag(p) >= target) return;
    __builtin_amdgcn_s_sleep(8);
  }
}

// ---------------------------------------------------------------------------
// One-shot fp32 -> f16 conversion for ALL three tensors in one launch
// (x 8388608 | w_ih0 131072 | w_ih1 262144 elements) — memory-bound,
// consolidates three tiny launches into one.
#define N_X   (B_ * T_ * DIN_)          // 8388608
#define N_W0  (H_ * DIN_)               // 131072
#define N_W1  (H_ * H_)                 // 262144
__global__ void cvt_all(const float* __restrict__ x, const float* __restrict__ w0,
                        const float* __restrict__ w1, _Float16* __restrict__ ox,
                        _Float16* __restrict__ o0, _Float16* __restrict__ o1) {
  int idx = blockIdx.x * 256 + threadIdx.x;
  if (idx < N_X) {
    ox[idx] = (_Float16)x[idx];
  } else if (idx < N_X + N_W0) {
    int i = idx - N_X;
    o0[i] = (_Float16)w0[i];
  } else if (idx < N_X + N_W0 + N_W1) {
    int i = idx - N_X - N_W0;
    o1[i] = (_Float16)w1[i];
  }
}

// ---------------------------------------------------------------------------
// Prep: convert W_hh (fp32, row-major HxH) into the R2 4-split scan layout:
//   chunk c = (rsub*16 + i)*512 + tid  holds  W[4*(tid&127)+rsub][(tid>>7)*16+i chunk]
// Scan thread tid loads chunk (rsub,i) at lane-stride 16 B -> fully coalesced.
// Also zeroes the 32 pipeline flags (block 0) — folded-in launch.
__global__ void prep_w(const float* __restrict__ w0, const float* __restrict__ w1,
                       _Float16* __restrict__ o0, _Float16* __restrict__ o1,
                       unsigned* __restrict__ flags) {
  if (blockIdx.x == 0 && threadIdx.x < 2 * NCHUNK) flags[threadIdx.x] = 0u;
  int idx = blockIdx.x * 256 + threadIdx.x;        // 0 .. 65535 (two matrices)
  const float* src = (idx < 32768) ? w0 : w1;
  _Float16* dst = (idx < 32768) ? o0 : o1;
  int c = idx & 32767;
  int tid  = c & 511;
  int rest = c >> 9;          // 0..63
  int i    = rest & 15;
  int rsub = rest >> 4;       // 0..3
  int row = 4 * (tid & 127) + rsub;
  int kc  = (tid >> 7) * 16 + i;
#pragma unroll
  for (int e = 0; e < 8; ++e)
    dst[(size_t)c * 8 + e] = (_Float16)src[row * 512 + kc * 8 + e];
}

// ---------------------------------------------------------------------------
// GEMM: out[m,n] = sum_k X[m,k]*W[n,k] + bias1[n] + bias2[n], written as f16.
// 128x128 tile / 256 threads / 4 waves (2x2 of 64x64), BK=32 (for xproj0 only).
__global__ __launch_bounds__(256)
void gemm_xproj(const _Float16* __restrict__ X,
                const _Float16* __restrict__ W,
                const float* __restrict__ bias1,
                const float* __restrict__ bias2,
                _Float16* __restrict__ out, int K) {
  __shared__ __align__(16) _Float16 As[128 * 32];
  __shared__ __align__(16) _Float16 Bs[128 * 32];
  const int tid  = threadIdx.x;
  const int wave = tid >> 6;
  const int lane = tid & 63;
  const int wr = wave >> 1, wc = wave & 1;
  const int m0 = blockIdx.x * 128, n0 = blockIdx.y * 128;
  const int fr = lane & 15;
  const int fk = (lane >> 4) * 8;
  const int cA = (lane & 3) * 8;
  const int rsub = lane >> 2;

  f32x4 acc[4][4];
#pragma unroll
  for (int a = 0; a < 4; ++a)
#pragma unroll
    for (int b = 0; b < 4; ++b)
      acc[a][b] = (f32x4){0.f, 0.f, 0.f, 0.f};

  for (int k0 = 0; k0 < K; k0 += 32) {
    __syncthreads();
#pragma unroll
    for (int q = 0; q < 2; ++q) {
      int p = wave * 2 + q;
      int r = p * 16 + rsub;
      const _Float16* gA = X + (size_t)(m0 + r) * K + (k0 + cA);
      const _Float16* gB = W + (size_t)(n0 + r) * K + (k0 + cA);
      __builtin_amdgcn_global_load_lds(
          (const __attribute__((address_space(1))) void*)gA,
          (__attribute__((address_space(3))) void*)((char*)As + p * 1024), 16, 0, 0);
      __builtin_amdgcn_global_load_lds(
          (const __attribute__((address_space(1))) void*)gB,
          (__attribute__((address_space(3))) void*)((char*)Bs + p * 1024), 16, 0, 0);
    }
    __syncthreads();

    f16x8 af[4], bfr[4];
#pragma unroll
    for (int mt = 0; mt < 4; ++mt)
      af[mt] = *(const f16x8*)&As[(wr * 64 + mt * 16 + fr) * 32 + fk];
#pragma unroll
    for (int nt = 0; nt < 4; ++nt)
      bfr[nt] = *(const f16x8*)&Bs[(wc * 64 + nt * 16 + fr) * 32 + fk];
#pragma unroll
    for (int mt = 0; mt < 4; ++mt)
#pragma unroll
      for (int nt = 0; nt < 4; ++nt)
        acc[mt][nt] = __builtin_amdgcn_mfma_f32_16x16x32_f16(af[mt], bfr[nt], acc[mt][nt], 0, 0, 0);
  }

  const int col = lane & 15, rq = lane >> 4;
#pragma unroll
  for (int nt = 0; nt < 4; ++nt) {
    int n = n0 + wc * 64 + nt * 16 + col;
    float bias = bias1[n] + bias2[n];
#pragma unroll
    for (int mt = 0; mt < 4; ++mt) {
      int mbase = m0 + wr * 64 + mt * 16 + rq * 4;
#pragma unroll
      for (int r = 0; r < 4; ++r)
        out[(size_t)(mbase + r) * H_ + n] = (_Float16)(acc[mt][nt][r] + bias);
    }
  }
}

// ---------------------------------------------------------------------------
// Scan role — the R5 champion configuration (best verified: fused 1110 us,
// total 1202 us), restored verbatim after R6-R10 experiments all came back
// null or worse:
//   slots  0..31 (row+0,row+1)   -> wreg[32] = 128 VGPR
//   slots 32..47 (row+2, ALL i)  -> 128 KB LDS-resident
//   slots 48..63 (row+3)         -> streamed from L2, one 4-deep ring
// Lean barriers (lgkmcnt-only) both phases; full __syncthreads only at
// chunk boundaries. 138 KB LDS forces 1 WG/CU.
// Plateau note (R2..R10): step time is pinned at ~2.05-2.15 us across all
// residency mixes, packing modes, register budgets, and barrier counts —
// a latency-bound local minimum of this per-batch-WG decomposition.
__device__ __forceinline__ void scan_role(
    int layer, int b,
    const uint4* __restrict__ Wg, const _Float16* __restrict__ xproj,
    _Float16* __restrict__ seq, float* __restrict__ hlast,
    unsigned* __restrict__ ca, unsigned* __restrict__ cb, char* smem)
{
  uint4* ldsW = (uint4*)smem;                                  // 128 KB (slots 32..47)
  float (*psum)[512] = (float (*)[512])(smem + 131072);        // 8 KB k-quarter partials
  _Float16 (*hb)[512] = (_Float16 (*)[512])(smem + 139264);    // 2 KB h double buffer
  const int tid = threadIdx.x;
  const int u = tid >> 7;                                      // k-quarter 0..3

  // slots 0..31 (rows +0,+1) -> 128 VGPRs, coalesced (lane stride 16 B)
  uint4 wreg[32];
#pragma unroll
  for (int i = 0; i < 32; ++i) wreg[i] = Wg[i * 512 + tid];
#pragma unroll
  for (int i = 0; i < 32; ++i) pin4(wreg[i]);

  // slots 32..47 (row+2, i=0..15) -> LDS (one-time, coalesced)
#pragma unroll
  for (int i = 0; i < 16; ++i) ldsW[i * 512 + tid] = Wg[(32 + i) * 512 + tid];

  hb[0][tid] = (_Float16)0.f;
  hb[1][tid] = (_Float16)0.f;
  __syncthreads();

  const uint4* S3 = Wg + (size_t)48 * 512 + tid;    // row+3, i=0..15 (16 slots)
  const _Float16* xp = xproj + (size_t)b * (T_ * H_) + tid;
  _Float16* sq = seq + (size_t)b * (T_ * H_) + tid;

  int cur = 0;
  for (int t = 0; t < T_; ++t) {
    if (layer == 1 && (t & (CHUNK - 1)) == 0) {
      // acquire chunk t/CHUNK of xproj1
      if (tid == 0) wait_flag(cb + (t / CHUNK), NGEMM);
      __syncthreads();
      __threadfence();                              // inv stale L1/L2 lines
    }
    float xv = (float)xp[(size_t)t * H_];           // in-register across barrier A
    const uint4* hbu = (const uint4*)hb[cur] + u * 16;

    // prefill the 4-deep ring (4 outstanding loads; 12 reloads in-loop)
    uint4 q3[4];
#pragma unroll
    for (int p = 0; p < 4; ++p) q3[p] = S3[(size_t)p * 512];

    float a0 = 0.f, a1 = 0.f, a2 = 0.f, a3 = 0.f;   // row accumulators = 4 chains
#pragma unroll
    for (int i = 0; i < 16; ++i) {
      uint4 h = hbu[i];                             // one b128 broadcast read
      a0 = dot8(wreg[i], h, a0);
      a1 = dot8(wreg[16 + i], h, a1);
      a2 = dot8(ldsW[i * 512 + tid], h, a2);        // dense 16-B stride, conflict-free
      a3 = dot8(q3[i & 3], h, a3);
      if (i + 4 < 16) q3[i & 3] = S3[(size_t)(i + 4) * 512];
    }
    // psum[u][4r+rsub]: one contiguous b128 per thread, conflict-free
    *(f32x4*)&psum[u][4 * (tid & 127)] = (f32x4){a0, a1, a2, a3};
    barrier_lds();                                  // A: partials visible (DS only)

    // reduce: thread tid owns row tid (lane-stride-4B reads, 2-way = free)
    float s = (psum[0][tid] + psum[1][tid]) + (psum[2][tid] + psum[3][tid]);
    float hn = fast_tanh(s + xv);
    _Float16 h16 = (_Float16)hn;
    hb[cur ^ 1][tid] = h16;
    if (layer == 0) {
      sq[(size_t)t * H_] = h16;
    } else if (t == T_ - 1) {
      hlast[b * H_ + tid] = hn;
    }
    if (layer == 0 && (t & (CHUNK - 1)) == CHUNK - 1) {
      // chunk boundary: drain seq stores (vmcnt) before publishing
      __syncthreads();
      if (tid == 0) { __threadfence(); add_flag(ca + (t / CHUNK)); }
    } else {
      barrier_lds();                                // B: hb[cur^1] complete (DS only)
    }
    cur ^= 1;
  }
}

// ---------------------------------------------------------------------------
// GEMM worker role: per chunk c, WG g computes one 128x128 tile of
// xproj1 = h1seq @ W_ih1^T + b_ih1 + b_hh1, writing IN PLACE over xproj0
// (safe: runs only after all L0 WGs finished — and thus finished reading —
// chunk c). 512 threads = 8 waves as 4x2 grid of 32x64 fragments.
__device__ __forceinline__ void gemm_role(
    int g,
    const _Float16* __restrict__ X,      // h1seq  (B,T,H) f16
    const _Float16* __restrict__ W,      // W_ih1  (H,H)   f16
    const float* __restrict__ bias1, const float* __restrict__ bias2,
    _Float16* __restrict__ out,          // xproj  (B,T,H) f16 (in-place)
    unsigned* __restrict__ ca, unsigned* __restrict__ cb, char* smem)
{
  _Float16* As = (_Float16*)smem;              // 8 KB [128][32]
  _Float16* Bs = (_Float16*)(smem + 8192);     // 8 KB [128][32]
  const int tid  = threadIdx.x;
  const int wave = tid >> 6;
  const int lane = tid & 63;
  const int wr = wave >> 1, wc = wave & 1;     // 4x2 waves, each 32 rows x 64 cols
  const int mt = g >> 2;                       // M-tile 0..15 (128 rows of 2048)
  const int n0 = (g & 3) * 128;
  const int fr = lane & 15;
  const int fk = (lane >> 4) * 8;
  const int sr  = tid >> 2;                    // staging row 0..127
  const int scq = (tid & 3) * 8;               // staging col (f16) 0/8/16/24
  const int col = lane & 15, rq = lane >> 4;
  const size_t wrow = (size_t)(n0 + sr) * H_ + scq;   // W staging addr (chunk-invariant)

  for (int c = 0; c < NCHUNK; ++c) {
    if (tid == 0) wait_flag(ca + c, B_);       // all 64 L0 WGs done with chunk c
    __syncthreads();
    __threadfence();                           // inv stale lines before reading h1seq

    // tile row jj -> batch 4*mt + (jj>>5), t = c*CHUNK + (jj&31)
    const size_t arow =
        ((size_t)(4 * mt + (sr >> 5)) * T_ + c * CHUNK + (sr & 31)) * H_ + scq;

    f32x4 acc[2][4];
#pragma unroll
    for (int m = 0; m < 2; ++m)
#pragma unroll
      for (int n = 0; n < 4; ++n)
        acc[m][n] = (f32x4){0.f, 0.f, 0.f, 0.f};

    for (int k0 = 0; k0 < H_; k0 += 32) {
      __syncthreads();
      __builtin_amdgcn_global_load_lds(
          (const __attribute__((address_space(1))) void*)(X + arow + k0),
          (__attribute__((address_space(3))) void*)((char*)As + (tid >> 6) * 1024), 16, 0, 0);
      __builtin_amdgcn_global_load_lds(
          (const __attribute__((address_space(1))) void*)(W + wrow + k0),
          (__attribute__((address_space(3))) void*)((char*)Bs + (tid >> 6) * 1024), 16, 0, 0);
      __syncthreads();                         // plain: NEEDS the vmcnt drain

      f16x8 af[2], bf[4];
#pragma unroll
      for (int m = 0; m < 2; ++m)
        af[m] = *(const f16x8*)&As[(wr * 32 + m * 16 + fr) * 32 + fk];
#pragma unroll
      for (int n = 0; n < 4; ++n)
        bf[n] = *(const f16x8*)&Bs[(wc * 64 + n * 16 + fr) * 32 + fk];
#pragma unroll
      for (int m = 0; m < 2; ++m)
#pragma unroll
        for (int n = 0; n < 4; ++n)
          acc[m][n] = __builtin_amdgcn_mfma_f32_16x16x32_f16(af[m], bf[n], acc[m][n], 0, 0, 0);
    }

#pragma unroll
    for (int n = 0; n < 4; ++n) {
      int nn = n0 + wc * 64 + n * 16 + col;
      float bias = bias1[nn] + bias2[nn];
#pragma unroll
      for (int m = 0; m < 2; ++m) {
        int jbase = wr * 32 + m * 16 + rq * 4;
#pragma unroll
        for (int r = 0; r < 4; ++r) {
          int jj = jbase + r;
          size_t row = ((size_t)(4 * mt + (jj >> 5)) * T_ + c * CHUNK + (jj & 31)) * (size_t)H_;
          out[row + nn] = (_Float16)(acc[m][n][r] + bias);
        }
      }
    }
    __syncthreads();                           // drain all threads' tile stores
    if (tid == 0) { __threadfence(); add_flag(cb + c); }
  }
}

// ---------------------------------------------------------------------------
// Fused pipeline megakernel: 192 WGs x 512 threads, __launch_bounds__(512,1).
//   WG   0..63  : layer-0 scan (batch b)       — produces h1seq chunk flags ca[]
//   WG  64..127 : layer-1 scan (batch b-64)    — consumes xproj1 chunk flags cb[]
//   WG 128..191 : GEMM workers                 — ca[c] -> xproj1 tile -> cb[c]
// 138 KB LDS forces 1 WG/CU: 192 WGs <= 256 CUs all co-resident, one per CU;
// the wait DAG (L1 <- GEMM <- L0, L0 waits on nothing) is deadlock-free.
__global__ __launch_bounds__(512, 1)
void fused_pipeline(const uint4* __restrict__ Wg0, const uint4* __restrict__ Wg1,
                    const _Float16* __restrict__ Wih1,
                    const float* __restrict__ b_ih1, const float* __restrict__ b_hh1,
                    _Float16* __restrict__ xproj, _Float16* __restrict__ h1seq,
                    float* __restrict__ hlast, unsigned* __restrict__ flags) {
  __shared__ __align__(16) char smem[141312];
  unsigned* ca = flags;            // [NCHUNK] target B_
  unsigned* cb = flags + NCHUNK;   // [NCHUNK] target NGEMM
  const int wg = blockIdx.x;
  if (wg < 64) {
    scan_role(0, wg, Wg0, xproj, h1seq, hlast, ca, cb, smem);
  } else if (wg < 128) {
    scan_role(1, wg - 64, Wg1, xproj, h1seq, hlast, ca, cb, smem);
  } else {
    gemm_role(wg - 128, h1seq, Wih1, b_ih1, b_hh1, xproj, ca, cb, smem);
  }
}

// ---------------------------------------------------------------------------
// Final FC: out[b,o] = h2[b,:] . w_fc[o,:] + b_fc[o]   (64 x 128, tiny, pure fp32)
__global__ void fc_kernel(const float* __restrict__ h2,
                          const float* __restrict__ wfc,
                          const float* __restrict__ bfc,
                          float* __restrict__ out) {
  int b = blockIdx.x, o = threadIdx.x;
  float s = bfc[o];
  const float* hv = h2 + b * H_;
  const float* wr = wfc + (size_t)o * H_;
#pragma unroll 8
  for (int k = 0; k < H_; ++k) s += hv[k] * wr[k];
  out[b * DOUT_ + o] = s;
}

// ---------------------------------------------------------------------------
extern "C" void kernel_launch(void* const* d_in, const int* in_sizes, int n_in,
                              void* d_out, int out_size, void* d_ws, size_t ws_size,
                              hipStream_t stream) {
  const float* x     = (const float*)d_in[0];
  const float* w_ih0 = (const float*)d_in[1];
  const float* w_hh0 = (const float*)d_in[2];
  const float* b_ih0 = (const float*)d_in[3];
  const float* b_hh0 = (const float*)d_in[4];
  const float* w_ih1 = (const float*)d_in[5];
  const float* w_hh1 = (const float*)d_in[6];
  const float* b_ih1 = (const float*)d_in[7];
  const float* b_hh1 = (const float*)d_in[8];
  const float* w_fc  = (const float*)d_in[9];
  const float* b_fc  = (const float*)d_in[10];

  char* ws = (char*)d_ws;
  _Float16* Ws0   = (_Float16*)(ws + 0);          // 512 KB  (w_hh0 scan layout)
  _Float16* Ws1   = (_Float16*)(ws + 524288);     // 512 KB  (w_hh1 scan layout)
  _Float16* Wih0  = (_Float16*)(ws + 1048576);    // 256 KB  (w_ih0 f16)
  _Float16* Wih1  = (_Float16*)(ws + 1310720);    // 512 KB  (w_ih1 f16)
  float*    h2    = (float*)   (ws + 2097152);    // 128 KB  (final hidden, fp32)
  unsigned* flags = (unsigned*)(ws + 3145728);    // 128 B   (chunk counters)
  _Float16* xproj = (_Float16*)(ws + 4194304);    // 32 MB   (xproj0, overwritten by xproj1)
  _Float16* xf16  = (_Float16*)(ws + 37748736);   // x as f16, then dead...
  _Float16* h1seq = (_Float16*)(ws + 37748736);   // ...h1 sequence f16 (32 MB)

  // 1) one-shot conversions (x, w_ih0, w_ih1 in ONE launch) + scan-layout
  //    prep for both W_hh (flags zeroed inside prep_w's block 0)
  cvt_all<<<(N_X + N_W0 + N_W1 + 255) / 256, 256, 0, stream>>>(
      x, w_ih0, w_ih1, xf16, Wih0, Wih1);
  prep_w<<<256, 256, 0, stream>>>(w_hh0, w_hh1, Ws0, Ws1, flags);

  // 2) xproj0 = x @ w_ih0^T + b_ih0 + b_hh0   (M=32768, K=256)
  gemm_xproj<<<dim3(256, 4), 256, 0, stream>>>(xf16, Wih0, b_ih0, b_hh0, xproj, DIN_);

  // 3+4+5) fused: layer-0 scan || chunked xproj1 GEMM || layer-1 scan
  fused_pipeline<<<192, 512, 0, stream>>>((const uint4*)Ws0, (const uint4*)Ws1,
                                          Wih1, b_ih1, b_hh1,
                                          xproj, h1seq, h2, flags);

  // 6) FC -> d_out (fp32, 64x128)
  fc_kernel<<<B_, DOUT_, 0, stream>>>(h2, w_fc, b_fc, (float*)d_out);
}